// Round 14
// baseline (25260.010 us; speedup 1.0000x reference)
//
#include <hip/hip_runtime.h>
#include <hip/hip_bf16.h>
#include <hip/hip_cooperative_groups.h>

namespace cg = cooperative_groups;
typedef __hip_bfloat16 bf16;

constexpr int NV=1024, TT=24, BB=8, CAP=80;

// ---- ws layout (float offsets) ---- node-major fields [b][n][C]
constexpr int O_CVAL = 0;               // 2048*80
constexpr int O_CIDX = 163840;          // 2048*80 ints
constexpr int O_CCNT = 327680;          // 2048 ints
constexpr int O_LIWT = 329728;          // 66*64  k-major [k][c]
constexpr int O_GCWT = 333952;          // 128*64
constexpr int O_LOWT = 342144;          // 128*64
constexpr int O_FWT  = 350336;          // 330*64
constexpr int O_UWT  = 371456;          // 330*64
constexpr int O_CWT  = 392576;          // 330*64
constexpr int O_H    = 413696;          // [b][n][64]   (fallback path)
constexpr int O_T1   = 937984;          // xin ; XC aliases
constexpr int O_T3   = 1986560;         // U (fallback)
constexpr int O_XH   = 2510848;         // [b][n][68] (66 used)
constexpr int O_Z1F  = 3067904;
constexpr int O_Z1B  = 3624960;
constexpr int O_PART = 4182016;         // [8][1024] float2 per-(b,n) partials
constexpr int O_RST  = 5296144;         // bf16 [24][8][1024][128]
constexpr int O_SST  = 17879056;        // bf16 [24][8][1024][64]
constexpr size_t WS_FLOATS = 24170512;
constexpr int O_XC = O_T1;
constexpr int O_U  = O_T3;

// ---- output layout (f32 elements) ----
constexpr int OFF_IMP  = 0;
constexpr int OFF_PRED = 196608;
constexpr int OFF_REPR = 393216;
constexpr int OFF_ST   = 25559040;

__device__ __forceinline__ bf16 f2b(float v){ return __float2bfloat16(v); }
__device__ __forceinline__ float b2f(bf16 v){ return __bfloat162float(v); }

__global__ __launch_bounds__(64) void k_csr(const float* __restrict__ adj, float* __restrict__ ws){
  int row = blockIdx.x, lane = threadIdx.x;
  const float* a = adj + (size_t)row*NV;
  float* val = ws + O_CVAL + (size_t)row*CAP;
  int* idx = (int*)(ws+O_CIDX) + (size_t)row*CAP;
  int count = 0;
  for(int ch=0; ch<NV/64; ++ch){
    float v = a[ch*64+lane];
    unsigned long long m = __ballot(v != 0.f);
    int pre = __popcll(m & ((1ull<<lane)-1ull));
    if(v != 0.f){ int p = count+pre; if(p<CAP){ idx[p]=ch*64+lane; val[p]=v; } }
    count += __popcll(m);
  }
  if(lane==0) ((int*)(ws+O_CCNT))[row] = count>CAP?CAP:count;
}

__global__ void k_prep_wt(const float* __restrict__ liW, const float* __restrict__ gcW,
    const float* __restrict__ loW, const float* __restrict__ fW,
    const float* __restrict__ uW, const float* __restrict__ cW, float* __restrict__ ws){
  int g = blockIdx.x*blockDim.x + threadIdx.x, G = gridDim.x*blockDim.x;
  for(int i=g;i<66*64;i+=G){ int k=i>>6, c=i&63; ws[O_LIWT+i]=liW[c*66+k]; }
  for(int i=g;i<128*64;i+=G){ int k=i>>6, c=i&63; ws[O_GCWT+i]=gcW[c*128+k]; ws[O_LOWT+i]=loW[c*128+k]; }
  for(int i=g;i<330*64;i+=G){ int k=i>>6, c=i&63; ws[O_FWT+i]=fW[c*330+k]; ws[O_UWT+i]=uW[c*330+k]; ws[O_CWT+i]=cW[c*330+k]; }
}

__global__ __launch_bounds__(256) void k_h0(const float* __restrict__ h0, float* __restrict__ ws){
  int g = blockIdx.x*blockDim.x + threadIdx.x;
  if(g >= BB*NV*64) return;
  int c = g&63, n = (g>>6)&1023;
  ws[O_H + g] = h0[c*NV + n];
}

struct MegaP {
  const float *x, *mask, *h0, *fsW, *fsb, *li_b, *gcb, *lob, *prelu, *roW, *rob,
              *fb, *ub, *cb, *gng, *gnb;
  float *ws, *out;
};

// 66-ch prop of one node's 2 batch-columns: src field -> Z1F/Z1B
__device__ __forceinline__ void prop66_node(float* ws, int src, int n, int b0, int b1,
    int cnF, const int* idF, const float* vlF,
    int cnB, const int* idB, const float* vlB, int lane){
  bool hi = lane < 2;
  size_t c0 = (size_t)(b0*NV+n), c1 = (size_t)(b1*NV+n);
  float a00=0.f,a01=0.f,a10=0.f,a11=0.f;
  for(int k=0;k<cnF;++k){
    float a = vlF[k]; int ix = idF[k];
    const float* r0 = ws + src + (size_t)(b0*NV + ix)*68;
    const float* r1 = ws + src + (size_t)(b1*NV + ix)*68;
    a00 += a*r0[lane]; if(hi) a01 += a*r0[64+lane];
    a10 += a*r1[lane]; if(hi) a11 += a*r1[64+lane];
  }
  float* d0 = ws + O_Z1F + c0*68;
  float* d1 = ws + O_Z1F + c1*68;
  d0[lane]=a00; if(hi) d0[64+lane]=a01;
  d1[lane]=a10; if(hi) d1[64+lane]=a11;
  a00=0.f;a01=0.f;a10=0.f;a11=0.f;
  for(int k=0;k<cnB;++k){
    float a = vlB[k]; int ix = idB[k];
    const float* r0 = ws + src + (size_t)(b0*NV + ix)*68;
    const float* r1 = ws + src + (size_t)(b1*NV + ix)*68;
    a00 += a*r0[lane]; if(hi) a01 += a*r0[64+lane];
    a10 += a*r1[lane]; if(hi) a11 += a*r1[64+lane];
  }
  d0 = ws + O_Z1B + c0*68;
  d1 = ws + O_Z1B + c1*68;
  d0[lane]=a00; if(hi) d0[64+lane]=a01;
  d1[lane]=a10; if(hi) d1[64+lane]=a11;
}

__global__ __launch_bounds__(256, 2) void k_mega(MegaP p){
  cg::grid_group grid = cg::this_grid();
  float* ws = p.ws;
  __shared__ float vec[4][2][332];
  __shared__ float rs[256], rq[256];
  __shared__ float musd[8][2];
  int tid=threadIdx.x, wid=tid>>6, lane=tid&63;
  int b0 = wid*2, b1 = b0+1;
  int nbase = blockIdx.x*2;

  const int* ccnt = (const int*)(ws+O_CCNT);
  int cnF[2], cnB[2];
  const int *idF[2], *idB[2];
  const float *vlF[2], *vlB[2];
  for(int nn=0;nn<2;++nn){
    int n = nbase+nn;
    cnF[nn]=ccnt[n]; cnB[nn]=ccnt[NV+n];
    idF[nn]=(const int*)(ws+O_CIDX)+(size_t)n*CAP;
    vlF[nn]=ws+O_CVAL+(size_t)n*CAP;
    idB[nn]=(const int*)(ws+O_CIDX)+(size_t)(NV+n)*CAP;
    vlB[nn]=ws+O_CVAL+(size_t)(NV+n)*CAP;
  }

  float li_bl = p.li_b[lane], gcbl = p.gcb[lane], lobl = p.lob[lane];
  float fbl = p.fb[lane], ubl = p.ub[lane], cbl = p.cb[lane];
  float gngl = p.gng[lane], gnbl = p.gnb[lane];
  float fsWl = p.fsW[lane], fsb0 = p.fsb[0];
  float roW0 = p.roW[lane], roW1 = p.roW[64+lane], rob0 = p.rob[0];
  float pre0 = p.prelu[0];

  float h[2][2], u[2][2];
  for(int nn=0;nn<2;++nn){ h[nn][0] = p.h0[lane*NV + (nbase+nn)]; h[nn][1] = h[nn][0]; u[nn][0]=u[nn][1]=0.f; }

  const float2* part = (const float2*)(ws+O_PART);
  bf16* reprs = (bf16*)(ws + O_RST);
  bf16* sst = (bf16*)(ws + O_SST);
  float xm[2][2];

  for(int t=0; t<TT; ++t){
    // ===== phase A: (t>0: stats+norm+states) ; pred ; xin =====
    if(t > 0){
      for(int b=0;b<8;++b){
        float sx=0.f, sq=0.f;
        for(int i=tid;i<1024;i+=256){ float2 pp = part[b*1024+i]; sx+=pp.x; sq+=pp.y; }
        rs[tid]=sx; rq[tid]=sq; __syncthreads();
        for(int s=128;s;s>>=1){ if(tid<s){ rs[tid]+=rs[tid+s]; rq[tid]+=rq[tid+s]; } __syncthreads(); }
        if(tid==0){ float mu=rs[0]*(1.f/65536.f); float var=rq[0]*(1.f/65536.f)-mu*mu;
                    musd[b][0]=mu; musd[b][1]=rsqrtf(var+1e-5f); }
        __syncthreads();
      }
    }
    for(int nn=0;nn<2;++nn){
      int n = nbase+nn;
      size_t c0=(size_t)(b0*NV+n), c1=(size_t)(b1*NV+n);
      if(t > 0){
        h[nn][0] = (h[nn][0]-musd[b0][0])*musd[b0][1]*gngl + gnbl;
        h[nn][1] = (h[nn][1]-musd[b1][0])*musd[b1][1]*gngl + gnbl;
        sst[(size_t)(t-1)*(BB*NV*64) + c0*64 + lane] = f2b(h[nn][0]);
        sst[(size_t)(t-1)*(BB*NV*64) + c1*64 + lane] = f2b(h[nn][1]);
      }
      vec[wid][0][lane] = h[nn][0];
      vec[wid][1][lane] = h[nn][1];
      float pv0 = fsWl*h[nn][0], pv1 = fsWl*h[nn][1];
      #pragma unroll
      for(int off=32; off; off>>=1){ pv0 += __shfl_xor(pv0, off, 64); pv1 += __shfl_xor(pv1, off, 64); }
      float pred0 = pv0 + fsb0, pred1 = pv1 + fsb0;
      xm[nn][0] = p.mask[c0*TT+t]; xm[nn][1] = p.mask[c1*TT+t];
      float x10 = (xm[nn][0]>0.f)? p.x[c0*TT+t] : pred0;
      float x11 = (xm[nn][1]>0.f)? p.x[c1*TT+t] : pred1;
      if(lane==0){ p.out[OFF_PRED+c0*TT+t]=pred0; p.out[OFF_PRED+c1*TT+t]=pred1; }
      const float* Wt = ws + O_LIWT;
      float a0 = li_bl + Wt[lane]*x10 + Wt[64+lane]*xm[nn][0];
      float a1 = li_bl + Wt[lane]*x11 + Wt[64+lane]*xm[nn][1];
      for(int j=0;j<64;++j){
        float w = Wt[(2+j)*64+lane];
        a0 += w*vec[wid][0][j];
        a1 += w*vec[wid][1][j];
      }
      ws[O_T1 + c0*64 + lane] = a0;
      ws[O_T1 + c1*64 + lane] = a1;
    }
    grid.sync();

    // ===== phase B: prop64 ; gc ; lo+PReLU+repr ; ro+imp ; XH =====
    for(int nn=0;nn<2;++nn){
      int n = nbase+nn;
      size_t c0=(size_t)(b0*NV+n), c1=(size_t)(b1*NV+n);
      float pA=0.f,pB=0.f,qA=0.f,qB=0.f;
      for(int k=0;k<cnF[nn];++k){
        float a = vlF[nn][k]; int ix = idF[nn][k];
        pA += a*ws[O_T1 + (size_t)(b0*NV+ix)*64 + lane];
        pB += a*ws[O_T1 + (size_t)(b1*NV+ix)*64 + lane];
      }
      for(int k=0;k<cnB[nn];++k){
        float a = vlB[nn][k]; int ix = idB[nn][k];
        qA += a*ws[O_T1 + (size_t)(b0*NV+ix)*64 + lane];
        qB += a*ws[O_T1 + (size_t)(b1*NV+ix)*64 + lane];
      }
      vec[wid][0][lane]=pA; vec[wid][0][64+lane]=qA;
      vec[wid][1][lane]=pB; vec[wid][1][64+lane]=qB;
      const float* Gt = ws + O_GCWT;
      float g0 = gcbl, g1 = gcbl;
      for(int j=0;j<128;++j){
        float w = Gt[j*64+lane];
        g0 += w*vec[wid][0][j];
        g1 += w*vec[wid][1][j];
      }
      vec[wid][0][lane]=g0; vec[wid][0][64+lane]=h[nn][0];
      vec[wid][1][lane]=g1; vec[wid][1][64+lane]=h[nn][1];
      const float* Lt = ws + O_LOWT;
      float o0 = lobl, o1 = lobl;
      for(int j=0;j<128;++j){
        float w = Lt[j*64+lane];
        o0 += w*vec[wid][0][j];
        o1 += w*vec[wid][1][j];
      }
      o0 = (o0>=0.f)? o0 : pre0*o0;
      o1 = (o1>=0.f)? o1 : pre0*o1;
      size_t rb0o = (((size_t)t*BB + b0)*NV + n)*128;
      size_t rb1o = (((size_t)t*BB + b1)*NV + n)*128;
      reprs[rb0o + lane] = f2b(o0); reprs[rb0o + 64 + lane] = f2b(h[nn][0]);
      reprs[rb1o + lane] = f2b(o1); reprs[rb1o + 64 + lane] = f2b(h[nn][1]);
      float rv0 = roW0*o0 + roW1*h[nn][0];
      float rv1 = roW0*o1 + roW1*h[nn][1];
      #pragma unroll
      for(int off=32; off; off>>=1){ rv0 += __shfl_xor(rv0, off, 64); rv1 += __shfl_xor(rv1, off, 64); }
      float xs20 = rv0 + rob0, xs21 = rv1 + rob0;
      float x20 = (xm[nn][0]>0.f)? p.x[c0*TT+t] : xs20;
      float x21 = (xm[nn][1]>0.f)? p.x[c1*TT+t] : xs21;
      if(lane==0){ p.out[OFF_IMP+c0*TT+t]=xs20; p.out[OFF_IMP+c1*TT+t]=xs21; }
      float* xh0 = ws + O_XH + c0*68;
      float* xh1 = ws + O_XH + c1*68;
      xh0[2+lane] = h[nn][0]; xh1[2+lane] = h[nn][1];
      if(lane==0){ xh0[0]=x20; xh0[1]=xm[nn][0]; xh1[0]=x21; xh1[1]=xm[nn][1]; }
    }
    grid.sync();

    // ===== phase C: prop66 XH -> Z1F,Z1B =====
    for(int nn=0;nn<2;++nn)
      prop66_node(ws, O_XH, nbase+nn, b0, b1, cnF[nn], idF[nn], vlF[nn], cnB[nn], idB[nn], vlB[nn], lane);
    grid.sync();

    // ===== phase D: gates ; XC =====
    for(int nn=0;nn<2;++nn){
      int n = nbase+nn;
      size_t c0=(size_t)(b0*NV+n), c1=(size_t)(b1*NV+n);
      bool hi = lane < 2;
      const float* xh0 = ws + O_XH + c0*68;
      const float* xh1 = ws + O_XH + c1*68;
      const float* z1f0 = ws + O_Z1F + c0*68;
      const float* z1f1 = ws + O_Z1F + c1*68;
      const float* z1b0 = ws + O_Z1B + c0*68;
      const float* z1b1 = ws + O_Z1B + c1*68;
      vec[wid][0][lane]     = xh0[lane];  if(hi) vec[wid][0][64+lane]  = xh0[64+lane];
      vec[wid][1][lane]     = xh1[lane];  if(hi) vec[wid][1][64+lane]  = xh1[64+lane];
      vec[wid][0][66+lane]  = z1f0[lane]; if(hi) vec[wid][0][130+lane] = z1f0[64+lane];
      vec[wid][1][66+lane]  = z1f1[lane]; if(hi) vec[wid][1][130+lane] = z1f1[64+lane];
      vec[wid][0][198+lane] = z1b0[lane]; if(hi) vec[wid][0][262+lane] = z1b0[64+lane];
      vec[wid][1][198+lane] = z1b1[lane]; if(hi) vec[wid][1][262+lane] = z1b1[64+lane];
      float a00=0.f,a01=0.f,a10=0.f,a11=0.f;
      for(int k=0;k<cnF[nn];++k){
        float a = vlF[nn][k]; int ix = idF[nn][k];
        const float* r0 = ws + O_Z1F + (size_t)(b0*NV+ix)*68;
        const float* r1 = ws + O_Z1F + (size_t)(b1*NV+ix)*68;
        a00 += a*r0[lane]; if(hi) a01 += a*r0[64+lane];
        a10 += a*r1[lane]; if(hi) a11 += a*r1[64+lane];
      }
      vec[wid][0][132+lane]=a00; if(hi) vec[wid][0][196+lane]=a01;
      vec[wid][1][132+lane]=a10; if(hi) vec[wid][1][196+lane]=a11;
      a00=0.f;a01=0.f;a10=0.f;a11=0.f;
      for(int k=0;k<cnB[nn];++k){
        float a = vlB[nn][k]; int ix = idB[nn][k];
        const float* r0 = ws + O_Z1B + (size_t)(b0*NV+ix)*68;
        const float* r1 = ws + O_Z1B + (size_t)(b1*NV+ix)*68;
        a00 += a*r0[lane]; if(hi) a01 += a*r0[64+lane];
        a10 += a*r1[lane]; if(hi) a11 += a*r1[64+lane];
      }
      vec[wid][0][264+lane]=a00; if(hi) vec[wid][0][328+lane]=a01;
      vec[wid][1][264+lane]=a10; if(hi) vec[wid][1][328+lane]=a11;
      const float* Ft = ws + O_FWT;
      const float* Ut = ws + O_UWT;
      float ar0 = fbl, ar1 = fbl, au0 = ubl, au1 = ubl;
      for(int k=0;k<330;++k){
        float wf = Ft[k*64+lane];
        float wu = Ut[k*64+lane];
        float v0 = vec[wid][0][k], v1 = vec[wid][1][k];
        ar0 += wf*v0; ar1 += wf*v1;
        au0 += wu*v0; au1 += wu*v1;
      }
      float r0 = 1.f/(1.f+expf(-ar0)), r1 = 1.f/(1.f+expf(-ar1));
      u[nn][0] = 1.f/(1.f+expf(-au0));
      u[nn][1] = 1.f/(1.f+expf(-au1));
      float* xc0 = ws + O_XC + c0*68;
      float* xc1 = ws + O_XC + c1*68;
      xc0[2+lane] = r0*h[nn][0]; xc1[2+lane] = r1*h[nn][1];
      if(hi){ xc0[lane] = vec[wid][0][lane]; xc1[lane] = vec[wid][1][lane]; }
    }
    grid.sync();

    // ===== phase E: prop66 XC -> Z1F,Z1B =====
    for(int nn=0;nn<2;++nn)
      prop66_node(ws, O_XC, nbase+nn, b0, b1, cnF[nn], idF[nn], vlF[nn], cnB[nn], idB[nn], vlB[nn], lane);
    grid.sync();

    // ===== phase F: candidate ; h_new ; stats partials =====
    for(int nn=0;nn<2;++nn){
      int n = nbase+nn;
      size_t c0=(size_t)(b0*NV+n), c1=(size_t)(b1*NV+n);
      bool hi = lane < 2;
      const float* xc0 = ws + O_XC + c0*68;
      const float* xc1 = ws + O_XC + c1*68;
      const float* w1f0 = ws + O_Z1F + c0*68;
      const float* w1f1 = ws + O_Z1F + c1*68;
      const float* w1b0 = ws + O_Z1B + c0*68;
      const float* w1b1 = ws + O_Z1B + c1*68;
      vec[wid][0][lane]     = xc0[lane];  if(hi) vec[wid][0][64+lane]  = xc0[64+lane];
      vec[wid][1][lane]     = xc1[lane];  if(hi) vec[wid][1][64+lane]  = xc1[64+lane];
      vec[wid][0][66+lane]  = w1f0[lane]; if(hi) vec[wid][0][130+lane] = w1f0[64+lane];
      vec[wid][1][66+lane]  = w1f1[lane]; if(hi) vec[wid][1][130+lane] = w1f1[64+lane];
      vec[wid][0][198+lane] = w1b0[lane]; if(hi) vec[wid][0][262+lane] = w1b0[64+lane];
      vec[wid][1][198+lane] = w1b1[lane]; if(hi) vec[wid][1][262+lane] = w1b1[64+lane];
      float a00=0.f,a01=0.f,a10=0.f,a11=0.f;
      for(int k=0;k<cnF[nn];++k){
        float a = vlF[nn][k]; int ix = idF[nn][k];
        const float* r0 = ws + O_Z1F + (size_t)(b0*NV+ix)*68;
        const float* r1 = ws + O_Z1F + (size_t)(b1*NV+ix)*68;
        a00 += a*r0[lane]; if(hi) a01 += a*r0[64+lane];
        a10 += a*r1[lane]; if(hi) a11 += a*r1[64+lane];
      }
      vec[wid][0][132+lane]=a00; if(hi) vec[wid][0][196+lane]=a01;
      vec[wid][1][132+lane]=a10; if(hi) vec[wid][1][196+lane]=a11;
      a00=0.f;a01=0.f;a10=0.f;a11=0.f;
      for(int k=0;k<cnB[nn];++k){
        float a = vlB[nn][k]; int ix = idB[nn][k];
        const float* r0 = ws + O_Z1B + (size_t)(b0*NV+ix)*68;
        const float* r1 = ws + O_Z1B + (size_t)(b1*NV+ix)*68;
        a00 += a*r0[lane]; if(hi) a01 += a*r0[64+lane];
        a10 += a*r1[lane]; if(hi) a11 += a*r1[64+lane];
      }
      vec[wid][0][264+lane]=a00; if(hi) vec[wid][0][328+lane]=a01;
      vec[wid][1][264+lane]=a10; if(hi) vec[wid][1][328+lane]=a11;
      const float* Ct = ws + O_CWT;
      float ac0 = cbl, ac1 = cbl;
      for(int k=0;k<330;++k){
        float wc = Ct[k*64+lane];
        ac0 += wc*vec[wid][0][k];
        ac1 += wc*vec[wid][1][k];
      }
      float cd0 = tanhf(ac0), cd1 = tanhf(ac1);
      h[nn][0] = u[nn][0]*h[nn][0] + (1.f-u[nn][0])*cd0;
      h[nn][1] = u[nn][1]*h[nn][1] + (1.f-u[nn][1])*cd1;
      float s0 = h[nn][0], sq0 = s0*s0, s1 = h[nn][1], sq1 = s1*s1;
      #pragma unroll
      for(int off=32; off; off>>=1){
        s0 += __shfl_xor(s0, off, 64); sq0 += __shfl_xor(sq0, off, 64);
        s1 += __shfl_xor(s1, off, 64); sq1 += __shfl_xor(sq1, off, 64);
      }
      if(lane==0){
        ((float2*)(ws+O_PART))[b0*1024 + n] = make_float2(s0, sq0);
        ((float2*)(ws+O_PART))[b1*1024 + n] = make_float2(s1, sq1);
      }
    }
    grid.sync();
  }

  // ===== final: normalize t=23 states =====
  for(int b=0;b<8;++b){
    float sx=0.f, sq=0.f;
    for(int i=tid;i<1024;i+=256){ float2 pp = part[b*1024+i]; sx+=pp.x; sq+=pp.y; }
    rs[tid]=sx; rq[tid]=sq; __syncthreads();
    for(int s=128;s;s>>=1){ if(tid<s){ rs[tid]+=rs[tid+s]; rq[tid]+=rq[tid+s]; } __syncthreads(); }
    if(tid==0){ float mu=rs[0]*(1.f/65536.f); float var=rq[0]*(1.f/65536.f)-mu*mu;
                musd[b][0]=mu; musd[b][1]=rsqrtf(var+1e-5f); }
    __syncthreads();
  }
  for(int nn=0;nn<2;++nn){
    int n = nbase+nn;
    size_t c0=(size_t)(b0*NV+n), c1=(size_t)(b1*NV+n);
    float hh0 = (h[nn][0]-musd[b0][0])*musd[b0][1]*gngl + gnbl;
    float hh1 = (h[nn][1]-musd[b1][0])*musd[b1][1]*gngl + gnbl;
    sst[(size_t)23*(BB*NV*64) + c0*64 + lane] = f2b(hh0);
    sst[(size_t)23*(BB*NV*64) + c1*64 + lane] = f2b(hh1);
  }
}

// ======================= fallback kernels (round-12, proven) =======================

__global__ __launch_bounds__(256) void kA(float* __restrict__ ws,
    const float* __restrict__ x, const float* __restrict__ mask,
    const float* __restrict__ fsW, const float* __restrict__ fsb,
    const float* __restrict__ lib, const float* __restrict__ gng,
    const float* __restrict__ gnb, float* __restrict__ dout, int t){
  __shared__ float hs[4][2][64];
  __shared__ float rs[256], rq[256];
  __shared__ float musd[8][2];
  int tid = threadIdx.x, wid = tid>>6, lane = tid&63;
  int n = blockIdx.x;
  if(t > 0){
    const float2* part = (const float2*)(ws+O_PART);
    for(int b=0;b<8;++b){
      float sx=0.f, sq=0.f;
      for(int i=tid;i<1024;i+=256){ float2 p = part[b*1024+i]; sx+=p.x; sq+=p.y; }
      rs[tid]=sx; rq[tid]=sq; __syncthreads();
      for(int s=128;s;s>>=1){ if(tid<s){ rs[tid]+=rs[tid+s]; rq[tid]+=rq[tid+s]; } __syncthreads(); }
      if(tid==0){ float mu=rs[0]*(1.f/65536.f); float var=rq[0]*(1.f/65536.f)-mu*mu;
                  musd[b][0]=mu; musd[b][1]=rsqrtf(var+1e-5f); }
      __syncthreads();
    }
  }
  float gg = gng[lane], gb = gnb[lane];
  float x1v[2], xmv[2];
  #pragma unroll
  for(int j=0;j<2;++j){
    int b = wid*2+j;
    size_t col = (size_t)(b*NV+n);
    float h = ws[O_H + col*64 + lane];
    if(t > 0){
      h = (h - musd[b][0])*musd[b][1]*gg + gb;
      ws[O_H + col*64 + lane] = h;
      ((bf16*)(ws+O_SST))[(size_t)(t-1)*(BB*NV*64) + col*64 + lane] = f2b(h);
    }
    hs[wid][j][lane] = h;
    float pv = fsW[lane]*h;
    #pragma unroll
    for(int off=32; off; off>>=1) pv += __shfl_xor(pv, off, 64);
    float pred = pv + fsb[0];
    float xm = mask[col*TT + t];
    x1v[j] = (xm>0.f) ? x[col*TT + t] : pred;
    xmv[j] = xm;
    if(lane==0) dout[OFF_PRED + col*TT + t] = pred;
  }
  const float* Wt = ws + O_LIWT;
  float lb = lib[lane];
  float w0 = Wt[lane], w1 = Wt[64+lane];
  float a0 = lb + w0*x1v[0] + w1*xmv[0];
  float a1 = lb + w0*x1v[1] + w1*xmv[1];
  for(int j=0;j<64;++j){
    float w = Wt[(2+j)*64+lane];
    a0 += w*hs[wid][0][j];
    a1 += w*hs[wid][1][j];
  }
  ws[O_T1 + (size_t)((wid*2  )*NV+n)*64 + lane] = a0;
  ws[O_T1 + (size_t)((wid*2+1)*NV+n)*64 + lane] = a1;
}

__global__ __launch_bounds__(256) void kB(float* __restrict__ ws,
    const float* __restrict__ x, const float* __restrict__ mask,
    const float* __restrict__ gcb, const float* __restrict__ lob,
    const float* __restrict__ prelu, const float* __restrict__ roW,
    const float* __restrict__ rob, float* __restrict__ dout, int t){
  __shared__ float pq[4][2][128];
  int tid=threadIdx.x, wid=tid>>6, lane=tid&63;
  int n = blockIdx.x;
  int b0 = wid*2, b1 = wid*2+1;
  const int* ccnt = (const int*)(ws+O_CCNT);
  float p0=0.f,p1=0.f,q0=0.f,q1=0.f;
  {
    int cn = ccnt[n];
    const int* id = (const int*)(ws+O_CIDX) + (size_t)n*CAP;
    const float* vl = ws + O_CVAL + (size_t)n*CAP;
    for(int k=0;k<cn;++k){
      float a = vl[k]; int ix = id[k];
      p0 += a*ws[O_T1 + (size_t)(b0*NV+ix)*64 + lane];
      p1 += a*ws[O_T1 + (size_t)(b1*NV+ix)*64 + lane];
    }
  }
  {
    int cn = ccnt[NV+n];
    const int* id = (const int*)(ws+O_CIDX) + (size_t)(NV+n)*CAP;
    const float* vl = ws + O_CVAL + (size_t)(NV+n)*CAP;
    for(int k=0;k<cn;++k){
      float a = vl[k]; int ix = id[k];
      q0 += a*ws[O_T1 + (size_t)(b0*NV+ix)*64 + lane];
      q1 += a*ws[O_T1 + (size_t)(b1*NV+ix)*64 + lane];
    }
  }
  pq[wid][0][lane]=p0; pq[wid][0][64+lane]=q0;
  pq[wid][1][lane]=p1; pq[wid][1][64+lane]=q1;
  const float* Gt = ws + O_GCWT;
  float g0 = gcb[lane], g1 = g0;
  for(int j=0;j<128;++j){
    float w = Gt[j*64+lane];
    g0 += w*pq[wid][0][j];
    g1 += w*pq[wid][1][j];
  }
  float hv0 = ws[O_H + (size_t)(b0*NV+n)*64 + lane];
  float hv1 = ws[O_H + (size_t)(b1*NV+n)*64 + lane];
  pq[wid][0][lane]=g0; pq[wid][0][64+lane]=hv0;
  pq[wid][1][lane]=g1; pq[wid][1][64+lane]=hv1;
  const float* Lt = ws + O_LOWT;
  float o0 = lob[lane], o1 = o0;
  for(int j=0;j<128;++j){
    float w = Lt[j*64+lane];
    o0 += w*pq[wid][0][j];
    o1 += w*pq[wid][1][j];
  }
  float a = prelu[0];
  float r0 = roW[lane], r1 = roW[64+lane], rb0 = rob[0];
  bf16* reprs = (bf16*)(ws + O_RST);
  #pragma unroll
  for(int j=0;j<2;++j){
    int b = wid*2+j;
    float ov = (j? o1 : o0);
    float hv = (j? hv1 : hv0);
    ov = (ov>=0.f)? ov : a*ov;
    size_t col = (size_t)(b*NV+n);
    size_t rbo = (((size_t)t*BB + b)*NV + n)*128;
    reprs[rbo + lane]      = f2b(ov);
    reprs[rbo + 64 + lane] = f2b(hv);
    float rv = r0*ov + r1*hv;
    #pragma unroll
    for(int off=32; off; off>>=1) rv += __shfl_xor(rv, off, 64);
    float xs2 = rv + rb0;
    float xm = mask[col*TT+t];
    float x2 = (xm>0.f) ? x[col*TT+t] : xs2;
    if(lane==0) dout[OFF_IMP + col*TT + t] = xs2;
    float* xh = ws + O_XH + col*68;
    xh[2+lane] = hv;
    if(lane==0){ xh[0]=x2; xh[1]=xm; }
  }
}

__global__ __launch_bounds__(256) void k_prop(float* __restrict__ ws, int srcF, int srcB,
    int dstF, int dstB){
  int tid=threadIdx.x, wid = tid>>6, lane = tid&63;
  int n = blockIdx.x;
  int b0 = wid*2, b1 = wid*2+1;
  const int* ccnt = (const int*)(ws+O_CCNT);
  bool hi = lane < 2;
  {
    int cn = ccnt[n];
    const int* id = (const int*)(ws+O_CIDX) + (size_t)n*CAP;
    const float* vl = ws + O_CVAL + (size_t)n*CAP;
    float a00=0.f,a01=0.f,a10=0.f,a11=0.f;
    for(int k=0;k<cn;++k){
      float a = vl[k]; int ix = id[k];
      const float* r0 = ws + srcF + (size_t)(b0*NV + ix)*68;
      const float* r1 = ws + srcF + (size_t)(b1*NV + ix)*68;
      a00 += a*r0[lane]; if(hi) a01 += a*r0[64+lane];
      a10 += a*r1[lane]; if(hi) a11 += a*r1[64+lane];
    }
    float* d0 = ws + dstF + (size_t)(b0*NV+n)*68;
    float* d1 = ws + dstF + (size_t)(b1*NV+n)*68;
    d0[lane]=a00; if(hi) d0[64+lane]=a01;
    d1[lane]=a10; if(hi) d1[64+lane]=a11;
  }
  {
    int cn = ccnt[NV+n];
    const int* id = (const int*)(ws+O_CIDX) + (size_t)(NV+n)*CAP;
    const float* vl = ws + O_CVAL + (size_t)(NV+n)*CAP;
    float a00=0.f,a01=0.f,a10=0.f,a11=0.f;
    for(int k=0;k<cn;++k){
      float a = vl[k]; int ix = id[k];
      const float* r0 = ws + srcB + (size_t)(b0*NV + ix)*68;
      const float* r1 = ws + srcB + (size_t)(b1*NV + ix)*68;
      a00 += a*r0[lane]; if(hi) a01 += a*r0[64+lane];
      a10 += a*r1[lane]; if(hi) a11 += a*r1[64+lane];
    }
    float* d0 = ws + dstB + (size_t)(b0*NV+n)*68;
    float* d1 = ws + dstB + (size_t)(b1*NV+n)*68;
    d0[lane]=a00; if(hi) d0[64+lane]=a01;
    d1[lane]=a10; if(hi) d1[64+lane]=a11;
  }
}

__global__ __launch_bounds__(256) void kD(float* __restrict__ ws,
    const float* __restrict__ fb, const float* __restrict__ ub){
  __shared__ float vec[4][2][332];
  int tid=threadIdx.x, wid=tid>>6, lane=tid&63;
  int n = blockIdx.x;
  const int* ccnt = (const int*)(ws+O_CCNT);
  bool hi = lane < 2;
  #pragma unroll
  for(int j=0;j<2;++j){
    size_t col = (size_t)((wid*2+j)*NV+n);
    const float* xh  = ws + O_XH  + col*68;
    const float* z1f = ws + O_Z1F + col*68;
    const float* z1b = ws + O_Z1B + col*68;
    vec[wid][j][lane]     = xh[lane];   if(hi) vec[wid][j][64+lane]  = xh[64+lane];
    vec[wid][j][66+lane]  = z1f[lane];  if(hi) vec[wid][j][130+lane] = z1f[64+lane];
    vec[wid][j][198+lane] = z1b[lane];  if(hi) vec[wid][j][262+lane] = z1b[64+lane];
  }
  {
    int cn = ccnt[n];
    const int* id = (const int*)(ws+O_CIDX) + (size_t)n*CAP;
    const float* vl = ws + O_CVAL + (size_t)n*CAP;
    float a00=0.f,a01=0.f,a10=0.f,a11=0.f;
    for(int k=0;k<cn;++k){
      float a = vl[k]; int ix = id[k];
      const float* r0 = ws + O_Z1F + (size_t)((wid*2  )*NV+ix)*68;
      const float* r1 = ws + O_Z1F + (size_t)((wid*2+1)*NV+ix)*68;
      a00 += a*r0[lane]; if(hi) a01 += a*r0[64+lane];
      a10 += a*r1[lane]; if(hi) a11 += a*r1[64+lane];
    }
    vec[wid][0][132+lane]=a00; if(hi) vec[wid][0][196+lane]=a01;
    vec[wid][1][132+lane]=a10; if(hi) vec[wid][1][196+lane]=a11;
  }
  {
    int cn = ccnt[NV+n];
    const int* id = (const int*)(ws+O_CIDX) + (size_t)(NV+n)*CAP;
    const float* vl = ws + O_CVAL + (size_t)(NV+n)*CAP;
    float a00=0.f,a01=0.f,a10=0.f,a11=0.f;
    for(int k=0;k<cn;++k){
      float a = vl[k]; int ix = id[k];
      const float* r0 = ws + O_Z1B + (size_t)((wid*2  )*NV+ix)*68;
      const float* r1 = ws + O_Z1B + (size_t)((wid*2+1)*NV+ix)*68;
      a00 += a*r0[lane]; if(hi) a01 += a*r0[64+lane];
      a10 += a*r1[lane]; if(hi) a11 += a*r1[64+lane];
    }
    vec[wid][0][264+lane]=a00; if(hi) vec[wid][0][328+lane]=a01;
    vec[wid][1][264+lane]=a10; if(hi) vec[wid][1][328+lane]=a11;
  }
  const float* Ft = ws + O_FWT;
  const float* Ut = ws + O_UWT;
  float ar0 = fb[lane], ar1 = ar0;
  float au0 = ub[lane], au1 = au0;
  for(int k=0;k<330;++k){
    float wf = Ft[k*64+lane];
    float wu = Ut[k*64+lane];
    float v0 = vec[wid][0][k], v1 = vec[wid][1][k];
    ar0 += wf*v0; ar1 += wf*v1;
    au0 += wu*v0; au1 += wu*v1;
  }
  #pragma unroll
  for(int j=0;j<2;++j){
    size_t col = (size_t)((wid*2+j)*NV+n);
    float r = 1.f/(1.f+expf(-(j? ar1 : ar0)));
    float u = 1.f/(1.f+expf(-(j? au1 : au0)));
    float hv = ws[O_H + col*64 + lane];
    ws[O_U + col*64 + lane] = u;
    float* xc = ws + O_XC + col*68;
    xc[2+lane] = r*hv;
    if(hi) xc[lane] = vec[wid][j][lane];
  }
}

__global__ __launch_bounds__(256) void kF(float* __restrict__ ws, const float* __restrict__ cb){
  __shared__ float vec[4][2][332];
  int tid=threadIdx.x, wid=tid>>6, lane=tid&63;
  int n = blockIdx.x;
  const int* ccnt = (const int*)(ws+O_CCNT);
  bool hi = lane < 2;
  #pragma unroll
  for(int j=0;j<2;++j){
    size_t col = (size_t)((wid*2+j)*NV+n);
    const float* xc  = ws + O_XC  + col*68;
    const float* w1f = ws + O_Z1F + col*68;
    const float* w1b = ws + O_Z1B + col*68;
    vec[wid][j][lane]     = xc[lane];   if(hi) vec[wid][j][64+lane]  = xc[64+lane];
    vec[wid][j][66+lane]  = w1f[lane];  if(hi) vec[wid][j][130+lane] = w1f[64+lane];
    vec[wid][j][198+lane] = w1b[lane];  if(hi) vec[wid][j][262+lane] = w1b[64+lane];
  }
  {
    int cn = ccnt[n];
    const int* id = (const int*)(ws+O_CIDX) + (size_t)n*CAP;
    const float* vl = ws + O_CVAL + (size_t)n*CAP;
    float a00=0.f,a01=0.f,a10=0.f,a11=0.f;
    for(int k=0;k<cn;++k){
      float a = vl[k]; int ix = id[k];
      const float* r0 = ws + O_Z1F + (size_t)((wid*2  )*NV+ix)*68;
      const float* r1 = ws + O_Z1F + (size_t)((wid*2+1)*NV+ix)*68;
      a00 += a*r0[lane]; if(hi) a01 += a*r0[64+lane];
      a10 += a*r1[lane]; if(hi) a11 += a*r1[64+lane];
    }
    vec[wid][0][132+lane]=a00; if(hi) vec[wid][0][196+lane]=a01;
    vec[wid][1][132+lane]=a10; if(hi) vec[wid][1][196+lane]=a11;
  }
  {
    int cn = ccnt[NV+n];
    const int* id = (const int*)(ws+O_CIDX) + (size_t)(NV+n)*CAP;
    const float* vl = ws + O_CVAL + (size_t)(NV+n)*CAP;
    float a00=0.f,a01=0.f,a10=0.f,a11=0.f;
    for(int k=0;k<cn;++k){
      float a = vl[k]; int ix = id[k];
      const float* r0 = ws + O_Z1B + (size_t)((wid*2  )*NV+ix)*68;
      const float* r1 = ws + O_Z1B + (size_t)((wid*2+1)*NV+ix)*68;
      a00 += a*r0[lane]; if(hi) a01 += a*r0[64+lane];
      a10 += a*r1[lane]; if(hi) a11 += a*r1[64+lane];
    }
    vec[wid][0][264+lane]=a00; if(hi) vec[wid][0][328+lane]=a01;
    vec[wid][1][264+lane]=a10; if(hi) vec[wid][1][328+lane]=a11;
  }
  const float* Ct = ws + O_CWT;
  float ac0 = cb[lane], ac1 = ac0;
  for(int k=0;k<330;++k){
    float wc = Ct[k*64+lane];
    ac0 += wc*vec[wid][0][k];
    ac1 += wc*vec[wid][1][k];
  }
  #pragma unroll
  for(int j=0;j<2;++j){
    int b = wid*2+j;
    size_t col = (size_t)(b*NV+n);
    float cd = tanhf(j? ac1 : ac0);
    float hv = ws[O_H + col*64 + lane];
    float u  = ws[O_U + col*64 + lane];
    float hn = u*hv + (1.f-u)*cd;
    ws[O_H + col*64 + lane] = hn;
    float s = hn, sq = hn*hn;
    #pragma unroll
    for(int off=32; off; off>>=1){ s += __shfl_xor(s, off, 64); sq += __shfl_xor(sq, off, 64); }
    if(lane==0) ((float2*)(ws+O_PART))[b*1024 + n] = make_float2(s, sq);
  }
}

__global__ __launch_bounds__(256) void k_final(float* __restrict__ ws,
    const float* __restrict__ gng, const float* __restrict__ gnb){
  __shared__ float rs[256], rq[256];
  __shared__ float musd[8][2];
  int tid=threadIdx.x, wid=tid>>6, lane=tid&63;
  int n = blockIdx.x;
  const float2* part = (const float2*)(ws+O_PART);
  for(int b=0;b<8;++b){
    float sx=0.f, sq=0.f;
    for(int i=tid;i<1024;i+=256){ float2 p = part[b*1024+i]; sx+=p.x; sq+=p.y; }
    rs[tid]=sx; rq[tid]=sq; __syncthreads();
    for(int s=128;s;s>>=1){ if(tid<s){ rs[tid]+=rs[tid+s]; rq[tid]+=rq[tid+s]; } __syncthreads(); }
    if(tid==0){ float mu=rs[0]*(1.f/65536.f); float var=rq[0]*(1.f/65536.f)-mu*mu;
                musd[b][0]=mu; musd[b][1]=rsqrtf(var+1e-5f); }
    __syncthreads();
  }
  float gg=gng[lane], gb=gnb[lane];
  #pragma unroll
  for(int j=0;j<2;++j){
    int b = wid*2+j;
    size_t col = (size_t)(b*NV+n);
    float hn = ws[O_H + col*64 + lane];
    float h = (hn-musd[b][0])*musd[b][1]*gg + gb;
    ((bf16*)(ws+O_SST))[(size_t)23*(BB*NV*64) + col*64 + lane] = f2b(h);
  }
}

// transpose staging bf16 [t][b][n][CH] -> output f32 [b][CH][n][T]
__global__ __launch_bounds__(256) void k_transpose(const float* __restrict__ ws, float* __restrict__ dout,
                                                   int srcOff, int dstOff, int CH){
  __shared__ bf16 ld[32][16][26];
  int ct = CH/16;
  int per_b = 32*ct;
  int b = blockIdx.x / per_b;
  int r = blockIdx.x - b*per_b;
  int n0 = (r/ct)*32, ch0 = (r - (r/ct)*ct)*16;
  const bf16* src = (const bf16*)(ws + srcOff);
  for(int t=0;t<TT;++t){
    for(int i=threadIdx.x;i<512;i+=256){
      int cc=i&15, nn=i>>4;
      ld[nn][cc][t] = src[(((size_t)t*BB + b)*NV + n0+nn)*CH + ch0+cc];
    }
  }
  __syncthreads();
  for(int i=threadIdx.x;i<512;i+=256){
    int nn=i&31, cc=i>>5;
    size_t ob = ((size_t)(b*CH + ch0+cc)*NV + n0+nn)*TT;
    #pragma unroll
    for(int t=0;t<TT;++t) dout[dstOff + ob + t] = b2f(ld[nn][cc][t]);
  }
}

extern "C" void kernel_launch(void* const* d_in, const int* in_sizes, int n_in,
                              void* d_out, int out_size, void* d_ws, size_t ws_size,
                              hipStream_t stream){
  if(ws_size < WS_FLOATS * sizeof(float)) return;
  if(n_in < 23) return;

  float* ws = (float*)d_ws;
  float* out = (float*)d_out;

  const float* x    = (const float*)d_in[0];
  const float* mask = (const float*)d_in[1];
  const float* adj  = (const float*)d_in[2];
  const float* h0   = (const float*)d_in[3];
  const float* fsW  = (const float*)d_in[4];
  const float* fsb  = (const float*)d_in[5];
  const float* lib  = (const float*)d_in[7];
  const float* gcb  = (const float*)d_in[9];
  const float* lob  = (const float*)d_in[11];
  const float* roW  = (const float*)d_in[12];
  const float* rob  = (const float*)d_in[13];
  const float* prelu= (const float*)d_in[14];
  const float* fb   = (const float*)d_in[16];
  const float* ub   = (const float*)d_in[18];
  const float* cb   = (const float*)d_in[20];
  const float* gng  = (const float*)d_in[21];
  const float* gnb  = (const float*)d_in[22];

  k_csr    <<<dim3(2048), dim3(64),  0, stream>>>(adj, ws);
  k_prep_wt<<<dim3(64),   dim3(256), 0, stream>>>(
      (const float*)d_in[6], (const float*)d_in[8], (const float*)d_in[10],
      (const float*)d_in[15], (const float*)d_in[17], (const float*)d_in[19], ws);

  MegaP p;
  p.x = x; p.mask = mask; p.h0 = h0;
  p.fsW = fsW;  p.fsb = fsb;  p.li_b = lib;
  p.gcb = gcb;  p.lob = lob;
  p.roW = roW;  p.rob = rob;  p.prelu = prelu;
  p.fb = fb;    p.ub = ub;    p.cb = cb;
  p.gng = gng;  p.gnb = gnb;
  p.ws = ws;    p.out = out;

  void* kargs[] = { &p };
  hipError_t cerr = hipLaunchCooperativeKernel((const void*)k_mega, dim3(512), dim3(256),
                                               kargs, 0, stream);
  if(cerr != hipSuccess){
    // fallback: proven round-12 multi-kernel schedule
    k_h0<<<dim3(2048), dim3(256), 0, stream>>>(h0, ws);
    for(int t=0; t<TT; ++t){
      kA    <<<dim3(1024), dim3(256), 0, stream>>>(ws, x, mask, fsW, fsb, lib, gng, gnb, out, t);
      kB    <<<dim3(1024), dim3(256), 0, stream>>>(ws, x, mask, gcb, lob, prelu, roW, rob, out, t);
      k_prop<<<dim3(1024), dim3(256), 0, stream>>>(ws, O_XH, O_XH, O_Z1F, O_Z1B);
      kD    <<<dim3(1024), dim3(256), 0, stream>>>(ws, fb, ub);
      k_prop<<<dim3(1024), dim3(256), 0, stream>>>(ws, O_XC, O_XC, O_Z1F, O_Z1B);
      kF    <<<dim3(1024), dim3(256), 0, stream>>>(ws, cb);
    }
    k_final<<<dim3(1024), dim3(256), 0, stream>>>(ws, gng, gnb);
  }

  k_transpose<<<dim3(2048), dim3(256), 0, stream>>>(ws, out, O_RST, OFF_REPR, 128);
  k_transpose<<<dim3(1024), dim3(256), 0, stream>>>(ws, out, O_SST, OFF_ST, 64);
}

// Round 15
// 5158.392 us; speedup vs baseline: 4.8969x; 4.8969x over previous
//
#include <hip/hip_runtime.h>
#include <hip/hip_bf16.h>

typedef __hip_bfloat16 bf16;

constexpr int NV=1024, TT=24, BB=8, CAP=80;

// ---- ws layout (float offsets) ---- node-major fields [b][n][C]
constexpr int O_CVAL = 0;               // 2048*80
constexpr int O_CIDX = 163840;          // 2048*80 ints
constexpr int O_CCNT = 327680;          // 2048 ints
constexpr int O_LIWT = 329728;          // 66*64  k-major [k][c]
constexpr int O_GCWT = 333952;          // 128*64
constexpr int O_LOWT = 342144;          // 128*64
constexpr int O_FWT  = 350336;          // 330*64
constexpr int O_UWT  = 371456;          // 330*64
constexpr int O_CWT  = 392576;          // 330*64
constexpr int O_H    = 413696;          // [b][n][64]
constexpr int O_T1   = 937984;          // xin ; XC aliases
constexpr int O_T3   = 1986560;         // U
constexpr int O_XH   = 2510848;         // [b][n][68] (66 used)
constexpr int O_Z1F  = 3067904;
constexpr int O_Z1B  = 3624960;
constexpr int O_PART = 4182016;         // [8][1024] float2 per-(b,n) partials
constexpr int O_RST  = 5296144;         // bf16 [24][8][1024][128]
constexpr int O_SST  = 17879056;        // bf16 [24][8][1024][64]
constexpr size_t WS_FLOATS = 24170512;
constexpr int O_XC = O_T1;
constexpr int O_U  = O_T3;

// ---- output layout (f32 elements) ----
constexpr int OFF_IMP  = 0;
constexpr int OFF_PRED = 196608;
constexpr int OFF_REPR = 393216;
constexpr int OFF_ST   = 25559040;

__device__ __forceinline__ bf16 f2b(float v){ return __float2bfloat16(v); }
__device__ __forceinline__ float b2f(bf16 v){ return __bfloat162float(v); }

__global__ __launch_bounds__(64) void k_csr(const float* __restrict__ adj, float* __restrict__ ws){
  int row = blockIdx.x, lane = threadIdx.x;
  const float* a = adj + (size_t)row*NV;
  float* val = ws + O_CVAL + (size_t)row*CAP;
  int* idx = (int*)(ws+O_CIDX) + (size_t)row*CAP;
  int count = 0;
  for(int ch=0; ch<NV/64; ++ch){
    float v = a[ch*64+lane];
    unsigned long long m = __ballot(v != 0.f);
    int pre = __popcll(m & ((1ull<<lane)-1ull));
    if(v != 0.f){ int p = count+pre; if(p<CAP){ idx[p]=ch*64+lane; val[p]=v; } }
    count += __popcll(m);
  }
  if(lane==0) ((int*)(ws+O_CCNT))[row] = count>CAP?CAP:count;
}

__global__ void k_prep_wt(const float* __restrict__ liW, const float* __restrict__ gcW,
    const float* __restrict__ loW, const float* __restrict__ fW,
    const float* __restrict__ uW, const float* __restrict__ cW, float* __restrict__ ws){
  int g = blockIdx.x*blockDim.x + threadIdx.x, G = gridDim.x*blockDim.x;
  for(int i=g;i<66*64;i+=G){ int k=i>>6, c=i&63; ws[O_LIWT+i]=liW[c*66+k]; }
  for(int i=g;i<128*64;i+=G){ int k=i>>6, c=i&63; ws[O_GCWT+i]=gcW[c*128+k]; ws[O_LOWT+i]=loW[c*128+k]; }
  for(int i=g;i<330*64;i+=G){ int k=i>>6, c=i&63; ws[O_FWT+i]=fW[c*330+k]; ws[O_UWT+i]=uW[c*330+k]; ws[O_CWT+i]=cW[c*330+k]; }
}

__global__ __launch_bounds__(256) void k_h0(const float* __restrict__ h0, float* __restrict__ ws){
  int g = blockIdx.x*blockDim.x + threadIdx.x;
  if(g >= BB*NV*64) return;
  int c = g&63, n = (g>>6)&1023;
  ws[O_H + g] = h0[c*NV + n];
}

// kA: GroupNorm(t-1) finalize (half-wave per b) + states ; pred ; xin
__global__ __launch_bounds__(256) void kA(float* __restrict__ ws,
    const float* __restrict__ x, const float* __restrict__ mask,
    const float* __restrict__ fsW, const float* __restrict__ fsb,
    const float* __restrict__ lib, const float* __restrict__ gng,
    const float* __restrict__ gnb, float* __restrict__ dout, int t){
  __shared__ float hs[4][2][64];
  __shared__ float musd[8][2];
  int tid = threadIdx.x, wid = tid>>6, lane = tid&63;
  int n = blockIdx.x;
  if(t > 0){
    const float2* part = (const float2*)(ws+O_PART);
    int b = wid*2 + (lane>>5);
    int l5 = lane&31;
    float sx=0.f, sq=0.f;
    for(int i=l5;i<1024;i+=32){ float2 pp = part[b*1024+i]; sx+=pp.x; sq+=pp.y; }
    #pragma unroll
    for(int off=16;off;off>>=1){ sx+=__shfl_xor(sx,off,64); sq+=__shfl_xor(sq,off,64); }
    if(l5==0){ float mu=sx*(1.f/65536.f);
               musd[b][0]=mu; musd[b][1]=rsqrtf(sq*(1.f/65536.f)-mu*mu+1e-5f); }
    __syncthreads();
  }
  float gg = gng[lane], gb = gnb[lane];
  float x1v[2], xmv[2];
  #pragma unroll
  for(int j=0;j<2;++j){
    int b = wid*2+j;
    size_t col = (size_t)(b*NV+n);
    float h = ws[O_H + col*64 + lane];
    if(t > 0){
      h = (h - musd[b][0])*musd[b][1]*gg + gb;
      ws[O_H + col*64 + lane] = h;
      ((bf16*)(ws+O_SST))[(size_t)(t-1)*(BB*NV*64) + col*64 + lane] = f2b(h);
    }
    hs[wid][j][lane] = h;
    float pv = fsW[lane]*h;
    #pragma unroll
    for(int off=32; off; off>>=1) pv += __shfl_xor(pv, off, 64);
    float pred = pv + fsb[0];
    float xm = mask[col*TT + t];
    x1v[j] = (xm>0.f) ? x[col*TT + t] : pred;
    xmv[j] = xm;
    if(lane==0) dout[OFF_PRED + col*TT + t] = pred;
  }
  const float* Wt = ws + O_LIWT;
  float lb = lib[lane];
  float w0 = Wt[lane], w1 = Wt[64+lane];
  float a0 = lb + w0*x1v[0] + w1*xmv[0];
  float a1 = lb + w0*x1v[1] + w1*xmv[1];
  for(int j=0;j<64;++j){
    float w = Wt[(2+j)*64+lane];
    a0 += w*hs[wid][0][j];
    a1 += w*hs[wid][1][j];
  }
  ws[O_T1 + (size_t)((wid*2  )*NV+n)*64 + lane] = a0;
  ws[O_T1 + (size_t)((wid*2+1)*NV+n)*64 + lane] = a1;
}

// kB: prop64(T1) ; gc ; lo+PReLU+repr ; ro+imp ; XH
__global__ __launch_bounds__(256) void kB(float* __restrict__ ws,
    const float* __restrict__ x, const float* __restrict__ mask,
    const float* __restrict__ gcb, const float* __restrict__ lob,
    const float* __restrict__ prelu, const float* __restrict__ roW,
    const float* __restrict__ rob, float* __restrict__ dout, int t){
  __shared__ float pq[4][2][128];
  int tid=threadIdx.x, wid=tid>>6, lane=tid&63;
  int n = blockIdx.x;
  int b0 = wid*2, b1 = wid*2+1;
  const int* ccnt = (const int*)(ws+O_CCNT);
  float p0=0.f,p1=0.f,q0=0.f,q1=0.f;
  {
    int cn = ccnt[n];
    const int* id = (const int*)(ws+O_CIDX) + (size_t)n*CAP;
    const float* vl = ws + O_CVAL + (size_t)n*CAP;
    #pragma unroll 4
    for(int k=0;k<cn;++k){
      float a = vl[k]; int ix = id[k];
      p0 += a*ws[O_T1 + (size_t)(b0*NV+ix)*64 + lane];
      p1 += a*ws[O_T1 + (size_t)(b1*NV+ix)*64 + lane];
    }
  }
  {
    int cn = ccnt[NV+n];
    const int* id = (const int*)(ws+O_CIDX) + (size_t)(NV+n)*CAP;
    const float* vl = ws + O_CVAL + (size_t)(NV+n)*CAP;
    #pragma unroll 4
    for(int k=0;k<cn;++k){
      float a = vl[k]; int ix = id[k];
      q0 += a*ws[O_T1 + (size_t)(b0*NV+ix)*64 + lane];
      q1 += a*ws[O_T1 + (size_t)(b1*NV+ix)*64 + lane];
    }
  }
  pq[wid][0][lane]=p0; pq[wid][0][64+lane]=q0;
  pq[wid][1][lane]=p1; pq[wid][1][64+lane]=q1;
  const float* Gt = ws + O_GCWT;
  float g0 = gcb[lane], g1 = g0;
  for(int j=0;j<128;++j){
    float w = Gt[j*64+lane];
    g0 += w*pq[wid][0][j];
    g1 += w*pq[wid][1][j];
  }
  float hv0 = ws[O_H + (size_t)(b0*NV+n)*64 + lane];
  float hv1 = ws[O_H + (size_t)(b1*NV+n)*64 + lane];
  pq[wid][0][lane]=g0; pq[wid][0][64+lane]=hv0;
  pq[wid][1][lane]=g1; pq[wid][1][64+lane]=hv1;
  const float* Lt = ws + O_LOWT;
  float o0 = lob[lane], o1 = o0;
  for(int j=0;j<128;++j){
    float w = Lt[j*64+lane];
    o0 += w*pq[wid][0][j];
    o1 += w*pq[wid][1][j];
  }
  float a = prelu[0];
  float r0 = roW[lane], r1 = roW[64+lane], rb0 = rob[0];
  bf16* reprs = (bf16*)(ws + O_RST);
  #pragma unroll
  for(int j=0;j<2;++j){
    int b = wid*2+j;
    float ov = (j? o1 : o0);
    float hv = (j? hv1 : hv0);
    ov = (ov>=0.f)? ov : a*ov;
    size_t col = (size_t)(b*NV+n);
    size_t rbo = (((size_t)t*BB + b)*NV + n)*128;
    reprs[rbo + lane]      = f2b(ov);
    reprs[rbo + 64 + lane] = f2b(hv);
    float rv = r0*ov + r1*hv;
    #pragma unroll
    for(int off=32; off; off>>=1) rv += __shfl_xor(rv, off, 64);
    float xs2 = rv + rb0;
    float xm = mask[col*TT+t];
    float x2 = (xm>0.f) ? x[col*TT+t] : xs2;
    if(lane==0) dout[OFF_IMP + col*TT + t] = xs2;
    float* xh = ws + O_XH + col*68;
    xh[2+lane] = hv;
    if(lane==0){ xh[0]=x2; xh[1]=xm; }
  }
}

// prop66: dstF = fwd(srcF), dstB = bwd(srcB)
__global__ __launch_bounds__(256) void k_prop(float* __restrict__ ws, int srcF, int srcB,
    int dstF, int dstB){
  int tid=threadIdx.x, wid = tid>>6, lane = tid&63;
  int n = blockIdx.x;
  int b0 = wid*2, b1 = wid*2+1;
  const int* ccnt = (const int*)(ws+O_CCNT);
  bool hi = lane < 2;
  {
    int cn = ccnt[n];
    const int* id = (const int*)(ws+O_CIDX) + (size_t)n*CAP;
    const float* vl = ws + O_CVAL + (size_t)n*CAP;
    float a00=0.f,a01=0.f,a10=0.f,a11=0.f;
    #pragma unroll 4
    for(int k=0;k<cn;++k){
      float a = vl[k]; int ix = id[k];
      const float* r0 = ws + srcF + (size_t)(b0*NV + ix)*68;
      const float* r1 = ws + srcF + (size_t)(b1*NV + ix)*68;
      a00 += a*r0[lane]; if(hi) a01 += a*r0[64+lane];
      a10 += a*r1[lane]; if(hi) a11 += a*r1[64+lane];
    }
    float* d0 = ws + dstF + (size_t)(b0*NV+n)*68;
    float* d1 = ws + dstF + (size_t)(b1*NV+n)*68;
    d0[lane]=a00; if(hi) d0[64+lane]=a01;
    d1[lane]=a10; if(hi) d1[64+lane]=a11;
  }
  {
    int cn = ccnt[NV+n];
    const int* id = (const int*)(ws+O_CIDX) + (size_t)(NV+n)*CAP;
    const float* vl = ws + O_CVAL + (size_t)(NV+n)*CAP;
    float a00=0.f,a01=0.f,a10=0.f,a11=0.f;
    #pragma unroll 4
    for(int k=0;k<cn;++k){
      float a = vl[k]; int ix = id[k];
      const float* r0 = ws + srcB + (size_t)(b0*NV + ix)*68;
      const float* r1 = ws + srcB + (size_t)(b1*NV + ix)*68;
      a00 += a*r0[lane]; if(hi) a01 += a*r0[64+lane];
      a10 += a*r1[lane]; if(hi) a11 += a*r1[64+lane];
    }
    float* d0 = ws + dstB + (size_t)(b0*NV+n)*68;
    float* d1 = ws + dstB + (size_t)(b1*NV+n)*68;
    d0[lane]=a00; if(hi) d0[64+lane]=a01;
    d1[lane]=a10; if(hi) d1[64+lane]=a11;
  }
}

// kD: gates, 512 threads. wave-pair per batch-pair; halves split {stage+fwd | stage+bwd}
// gathers and split the K=330 dot (165 each); partials summed via LDS.
__global__ __launch_bounds__(512) void kD(float* __restrict__ ws,
    const float* __restrict__ fb, const float* __restrict__ ub){
  __shared__ float vec[4][2][332];
  __shared__ float acc[8][4][64];
  int tid=threadIdx.x, w=tid>>6, lane=tid&63;
  int pair=w>>1, half=w&1;
  int n = blockIdx.x;
  int b0 = pair*2, b1 = b0+1;
  size_t c0=(size_t)(b0*NV+n), c1=(size_t)(b1*NV+n);
  const int* ccnt = (const int*)(ws+O_CCNT);
  bool hi = lane < 2;
  if(half==0){
    const float* xh0 = ws + O_XH + c0*68;
    const float* xh1 = ws + O_XH + c1*68;
    const float* z1f0 = ws + O_Z1F + c0*68;
    const float* z1f1 = ws + O_Z1F + c1*68;
    vec[pair][0][lane]=xh0[lane];     if(hi) vec[pair][0][64+lane]=xh0[64+lane];
    vec[pair][1][lane]=xh1[lane];     if(hi) vec[pair][1][64+lane]=xh1[64+lane];
    vec[pair][0][66+lane]=z1f0[lane]; if(hi) vec[pair][0][130+lane]=z1f0[64+lane];
    vec[pair][1][66+lane]=z1f1[lane]; if(hi) vec[pair][1][130+lane]=z1f1[64+lane];
    int cn = ccnt[n];
    const int* id = (const int*)(ws+O_CIDX) + (size_t)n*CAP;
    const float* vl = ws + O_CVAL + (size_t)n*CAP;
    float a00=0.f,a01=0.f,a10=0.f,a11=0.f;
    #pragma unroll 4
    for(int k=0;k<cn;++k){
      float a = vl[k]; int ix = id[k];
      const float* r0 = ws + O_Z1F + (size_t)(b0*NV+ix)*68;
      const float* r1 = ws + O_Z1F + (size_t)(b1*NV+ix)*68;
      a00 += a*r0[lane]; if(hi) a01 += a*r0[64+lane];
      a10 += a*r1[lane]; if(hi) a11 += a*r1[64+lane];
    }
    vec[pair][0][132+lane]=a00; if(hi) vec[pair][0][196+lane]=a01;
    vec[pair][1][132+lane]=a10; if(hi) vec[pair][1][196+lane]=a11;
  } else {
    const float* z1b0 = ws + O_Z1B + c0*68;
    const float* z1b1 = ws + O_Z1B + c1*68;
    vec[pair][0][198+lane]=z1b0[lane]; if(hi) vec[pair][0][262+lane]=z1b0[64+lane];
    vec[pair][1][198+lane]=z1b1[lane]; if(hi) vec[pair][1][262+lane]=z1b1[64+lane];
    int cn = ccnt[NV+n];
    const int* id = (const int*)(ws+O_CIDX) + (size_t)(NV+n)*CAP;
    const float* vl = ws + O_CVAL + (size_t)(NV+n)*CAP;
    float a00=0.f,a01=0.f,a10=0.f,a11=0.f;
    #pragma unroll 4
    for(int k=0;k<cn;++k){
      float a = vl[k]; int ix = id[k];
      const float* r0 = ws + O_Z1B + (size_t)(b0*NV+ix)*68;
      const float* r1 = ws + O_Z1B + (size_t)(b1*NV+ix)*68;
      a00 += a*r0[lane]; if(hi) a01 += a*r0[64+lane];
      a10 += a*r1[lane]; if(hi) a11 += a*r1[64+lane];
    }
    vec[pair][0][264+lane]=a00; if(hi) vec[pair][0][328+lane]=a01;
    vec[pair][1][264+lane]=a10; if(hi) vec[pair][1][328+lane]=a11;
  }
  __syncthreads();
  const float* Ft = ws + O_FWT;
  const float* Ut = ws + O_UWT;
  int k0 = half*165, k1 = k0+165;
  float ar0 = half? 0.f : fb[lane];
  float au0 = half? 0.f : ub[lane];
  float ar1 = ar0, au1 = au0;
  for(int k=k0;k<k1;++k){
    float wf = Ft[k*64+lane];
    float wu = Ut[k*64+lane];
    float v0 = vec[pair][0][k], v1 = vec[pair][1][k];
    ar0 += wf*v0; ar1 += wf*v1;
    au0 += wu*v0; au1 += wu*v1;
  }
  acc[w][0][lane]=ar0; acc[w][1][lane]=ar1; acc[w][2][lane]=au0; acc[w][3][lane]=au1;
  __syncthreads();
  if(half==0){
    ar0 += acc[w+1][0][lane]; ar1 += acc[w+1][1][lane];
    au0 += acc[w+1][2][lane]; au1 += acc[w+1][3][lane];
    float r0 = 1.f/(1.f+expf(-ar0)), r1v = 1.f/(1.f+expf(-ar1));
    float u0 = 1.f/(1.f+expf(-au0)), u1v = 1.f/(1.f+expf(-au1));
    float hv0 = ws[O_H + c0*64 + lane];
    float hv1 = ws[O_H + c1*64 + lane];
    ws[O_U + c0*64 + lane] = u0;
    ws[O_U + c1*64 + lane] = u1v;
    float* xc0 = ws + O_XC + c0*68;
    float* xc1 = ws + O_XC + c1*68;
    xc0[2+lane] = r0*hv0; xc1[2+lane] = r1v*hv1;
    if(hi){ xc0[lane] = vec[pair][0][lane]; xc1[lane] = vec[pair][1][lane]; }
  }
}

// kF: candidate, 512 threads, same split; h_new ; per-(b,n) stats partials
__global__ __launch_bounds__(512) void kF(float* __restrict__ ws, const float* __restrict__ cb){
  __shared__ float vec[4][2][332];
  __shared__ float acc[8][2][64];
  int tid=threadIdx.x, w=tid>>6, lane=tid&63;
  int pair=w>>1, half=w&1;
  int n = blockIdx.x;
  int b0 = pair*2, b1 = b0+1;
  size_t c0=(size_t)(b0*NV+n), c1=(size_t)(b1*NV+n);
  const int* ccnt = (const int*)(ws+O_CCNT);
  bool hi = lane < 2;
  if(half==0){
    const float* xc0 = ws + O_XC + c0*68;
    const float* xc1 = ws + O_XC + c1*68;
    const float* w1f0 = ws + O_Z1F + c0*68;
    const float* w1f1 = ws + O_Z1F + c1*68;
    vec[pair][0][lane]=xc0[lane];      if(hi) vec[pair][0][64+lane]=xc0[64+lane];
    vec[pair][1][lane]=xc1[lane];      if(hi) vec[pair][1][64+lane]=xc1[64+lane];
    vec[pair][0][66+lane]=w1f0[lane];  if(hi) vec[pair][0][130+lane]=w1f0[64+lane];
    vec[pair][1][66+lane]=w1f1[lane];  if(hi) vec[pair][1][130+lane]=w1f1[64+lane];
    int cn = ccnt[n];
    const int* id = (const int*)(ws+O_CIDX) + (size_t)n*CAP;
    const float* vl = ws + O_CVAL + (size_t)n*CAP;
    float a00=0.f,a01=0.f,a10=0.f,a11=0.f;
    #pragma unroll 4
    for(int k=0;k<cn;++k){
      float a = vl[k]; int ix = id[k];
      const float* r0 = ws + O_Z1F + (size_t)(b0*NV+ix)*68;
      const float* r1 = ws + O_Z1F + (size_t)(b1*NV+ix)*68;
      a00 += a*r0[lane]; if(hi) a01 += a*r0[64+lane];
      a10 += a*r1[lane]; if(hi) a11 += a*r1[64+lane];
    }
    vec[pair][0][132+lane]=a00; if(hi) vec[pair][0][196+lane]=a01;
    vec[pair][1][132+lane]=a10; if(hi) vec[pair][1][196+lane]=a11;
  } else {
    const float* w1b0 = ws + O_Z1B + c0*68;
    const float* w1b1 = ws + O_Z1B + c1*68;
    vec[pair][0][198+lane]=w1b0[lane]; if(hi) vec[pair][0][262+lane]=w1b0[64+lane];
    vec[pair][1][198+lane]=w1b1[lane]; if(hi) vec[pair][1][262+lane]=w1b1[64+lane];
    int cn = ccnt[NV+n];
    const int* id = (const int*)(ws+O_CIDX) + (size_t)(NV+n)*CAP;
    const float* vl = ws + O_CVAL + (size_t)(NV+n)*CAP;
    float a00=0.f,a01=0.f,a10=0.f,a11=0.f;
    #pragma unroll 4
    for(int k=0;k<cn;++k){
      float a = vl[k]; int ix = id[k];
      const float* r0 = ws + O_Z1B + (size_t)(b0*NV+ix)*68;
      const float* r1 = ws + O_Z1B + (size_t)(b1*NV+ix)*68;
      a00 += a*r0[lane]; if(hi) a01 += a*r0[64+lane];
      a10 += a*r1[lane]; if(hi) a11 += a*r1[64+lane];
    }
    vec[pair][0][264+lane]=a00; if(hi) vec[pair][0][328+lane]=a01;
    vec[pair][1][264+lane]=a10; if(hi) vec[pair][1][328+lane]=a11;
  }
  __syncthreads();
  const float* Ct = ws + O_CWT;
  int k0 = half*165, k1 = k0+165;
  float ac0 = half? 0.f : cb[lane];
  float ac1 = ac0;
  for(int k=k0;k<k1;++k){
    float wc = Ct[k*64+lane];
    ac0 += wc*vec[pair][0][k];
    ac1 += wc*vec[pair][1][k];
  }
  acc[w][0][lane]=ac0; acc[w][1][lane]=ac1;
  __syncthreads();
  if(half==0){
    ac0 += acc[w+1][0][lane];
    ac1 += acc[w+1][1][lane];
    #pragma unroll
    for(int j=0;j<2;++j){
      int b = b0+j;
      size_t col = (j? c1 : c0);
      float cd = tanhf(j? ac1 : ac0);
      float hv = ws[O_H + col*64 + lane];
      float u  = ws[O_U + col*64 + lane];
      float hn = u*hv + (1.f-u)*cd;
      ws[O_H + col*64 + lane] = hn;
      float s = hn, sq = hn*hn;
      #pragma unroll
      for(int off=32; off; off>>=1){ s += __shfl_xor(s, off, 64); sq += __shfl_xor(sq, off, 64); }
      if(lane==0) ((float2*)(ws+O_PART))[b*1024 + n] = make_float2(s, sq);
    }
  }
}

// final: normalize t=23 states from PART (half-wave per b reduce)
__global__ __launch_bounds__(256) void k_final(float* __restrict__ ws,
    const float* __restrict__ gng, const float* __restrict__ gnb){
  __shared__ float musd[8][2];
  int tid=threadIdx.x, wid=tid>>6, lane=tid&63;
  int n = blockIdx.x;
  const float2* part = (const float2*)(ws+O_PART);
  {
    int b = wid*2 + (lane>>5);
    int l5 = lane&31;
    float sx=0.f, sq=0.f;
    for(int i=l5;i<1024;i+=32){ float2 pp = part[b*1024+i]; sx+=pp.x; sq+=pp.y; }
    #pragma unroll
    for(int off=16;off;off>>=1){ sx+=__shfl_xor(sx,off,64); sq+=__shfl_xor(sq,off,64); }
    if(l5==0){ float mu=sx*(1.f/65536.f);
               musd[b][0]=mu; musd[b][1]=rsqrtf(sq*(1.f/65536.f)-mu*mu+1e-5f); }
    __syncthreads();
  }
  float gg=gng[lane], gb=gnb[lane];
  #pragma unroll
  for(int j=0;j<2;++j){
    int b = wid*2+j;
    size_t col = (size_t)(b*NV+n);
    float hn = ws[O_H + col*64 + lane];
    float h = (hn-musd[b][0])*musd[b][1]*gg + gb;
    ((bf16*)(ws+O_SST))[(size_t)23*(BB*NV*64) + col*64 + lane] = f2b(h);
  }
}

// transpose staging bf16 [t][b][n][CH] -> output f32 [b][CH][n][T]
__global__ __launch_bounds__(256) void k_transpose(const float* __restrict__ ws, float* __restrict__ dout,
                                                   int srcOff, int dstOff, int CH){
  __shared__ bf16 ld[32][16][26];
  int ct = CH/16;
  int per_b = 32*ct;
  int b = blockIdx.x / per_b;
  int r = blockIdx.x - b*per_b;
  int n0 = (r/ct)*32, ch0 = (r - (r/ct)*ct)*16;
  const bf16* src = (const bf16*)(ws + srcOff);
  for(int t=0;t<TT;++t){
    for(int i=threadIdx.x;i<512;i+=256){
      int cc=i&15, nn=i>>4;
      ld[nn][cc][t] = src[(((size_t)t*BB + b)*NV + n0+nn)*CH + ch0+cc];
    }
  }
  __syncthreads();
  for(int i=threadIdx.x;i<512;i+=256){
    int nn=i&31, cc=i>>5;
    size_t ob = ((size_t)(b*CH + ch0+cc)*NV + n0+nn)*TT;
    #pragma unroll
    for(int t=0;t<TT;++t) dout[dstOff + ob + t] = b2f(ld[nn][cc][t]);
  }
}

extern "C" void kernel_launch(void* const* d_in, const int* in_sizes, int n_in,
                              void* d_out, int out_size, void* d_ws, size_t ws_size,
                              hipStream_t stream){
  if(ws_size < WS_FLOATS * sizeof(float)) return;
  if(n_in < 23) return;

  float* ws = (float*)d_ws;
  float* out = (float*)d_out;

  const float* x    = (const float*)d_in[0];
  const float* mask = (const float*)d_in[1];
  const float* adj  = (const float*)d_in[2];
  const float* h0   = (const float*)d_in[3];
  const float* fsW  = (const float*)d_in[4];
  const float* fsb  = (const float*)d_in[5];
  const float* lib  = (const float*)d_in[7];
  const float* gcb  = (const float*)d_in[9];
  const float* lob  = (const float*)d_in[11];
  const float* roW  = (const float*)d_in[12];
  const float* rob  = (const float*)d_in[13];
  const float* prelu= (const float*)d_in[14];
  const float* fb   = (const float*)d_in[16];
  const float* ub   = (const float*)d_in[18];
  const float* cb   = (const float*)d_in[20];
  const float* gng  = (const float*)d_in[21];
  const float* gnb  = (const float*)d_in[22];

  k_csr    <<<dim3(2048), dim3(64),  0, stream>>>(adj, ws);
  k_prep_wt<<<dim3(64),   dim3(256), 0, stream>>>(
      (const float*)d_in[6], (const float*)d_in[8], (const float*)d_in[10],
      (const float*)d_in[15], (const float*)d_in[17], (const float*)d_in[19], ws);
  k_h0     <<<dim3(2048), dim3(256), 0, stream>>>(h0, ws);

  for(int t=0; t<TT; ++t){
    kA    <<<dim3(1024), dim3(256), 0, stream>>>(ws, x, mask, fsW, fsb, lib, gng, gnb, out, t);
    kB    <<<dim3(1024), dim3(256), 0, stream>>>(ws, x, mask, gcb, lob, prelu, roW, rob, out, t);
    k_prop<<<dim3(1024), dim3(256), 0, stream>>>(ws, O_XH, O_XH, O_Z1F, O_Z1B);
    kD    <<<dim3(1024), dim3(512), 0, stream>>>(ws, fb, ub);
    k_prop<<<dim3(1024), dim3(256), 0, stream>>>(ws, O_XC, O_XC, O_Z1F, O_Z1B);
    kF    <<<dim3(1024), dim3(512), 0, stream>>>(ws, cb);
  }
  k_final<<<dim3(1024), dim3(256), 0, stream>>>(ws, gng, gnb);

  k_transpose<<<dim3(2048), dim3(256), 0, stream>>>(ws, out, O_RST, OFF_REPR, 128);
  k_transpose<<<dim3(1024), dim3(256), 0, stream>>>(ws, out, O_SST, OFF_ST, 64);
}